// Round 7
// baseline (2377.163 us; speedup 1.0000x reference)
//
#include <hip/hip_runtime.h>
#include <hip/hip_bf16.h>

#define B_TOT 2048
#define L_SEQ 2048
#define NBLK  256
#define BQ    8
#define NWAVE 8
#define XBS   328   // ushorts per XB row: 656B = 16B-aligned

typedef __attribute__((ext_vector_type(8))) short bf16x8;
typedef __attribute__((ext_vector_type(4))) float f32x4;

#if __has_builtin(__builtin_amdgcn_exp2f)
static __device__ __forceinline__ float fexp2(float x){ return __builtin_amdgcn_exp2f(x); }
#else
static __device__ __forceinline__ float fexp2(float x){ return exp2f(x); }
#endif
#if __has_builtin(__builtin_amdgcn_rcpf)
static __device__ __forceinline__ float frcp (float x){ return __builtin_amdgcn_rcpf(x); }
#else
static __device__ __forceinline__ float frcp (float x){ return 1.0f / x; }
#endif

static __device__ __forceinline__ unsigned short f2bf(float f){
  union { float f; unsigned int u; } v; v.f = f;
  unsigned int u = v.u;
  u += 0x7FFFu + ((u >> 16) & 1u);      // RTNE
  return (unsigned short)(u >> 16);
}
// pack bf16(a) low | bf16(b) high in one instruction (RTNE)
static __device__ __forceinline__ unsigned int cvtpk(float a, float b){
  unsigned int r;
  asm("v_cvt_pk_bf16_f32 %0, %1, %2" : "=v"(r) : "v"(a), "v"(b));
  return r;
}

static __device__ __forceinline__ float sigm_pre(float x, float bpre){
  return frcp(1.f + fexp2(__builtin_fmaf(x, -1.4426950408889634f, bpre)));
}
static __device__ __forceinline__ float tanh_pre(float x, float bpre){
  return 1.f - 2.f*frcp(1.f + fexp2(__builtin_fmaf(x, 2.8853900817779268f, bpre)));
}
static __device__ __forceinline__ float cell_act(float gi,float gf,float gg,float go,
    float bi,float bf,float bg,float bo, float& c, bool act){
  float is = sigm_pre(gi, bi);
  float fs = sigm_pre(gf, bf);
  float gt = tanh_pre(gg, bg);
  float os = sigm_pre(go, bo);
  float cn = __builtin_fmaf(fs, c, is*gt);
  float h  = os * tanh_pre(cn, 0.f);
  c = act ? cn : 0.f;                    // new_cs = where(active, c', 0)
  return h;                              // RAW h (masking done at next-step read)
}

// One fully-unrolled timestep; PAR must be a literal 0/1 so all LDS offsets
// are compile-time immediates.
#define STEP(PAR, TCUR)                                                         \
  {                                                                             \
    const int  t_   = (TCUR);                                                   \
    const int  tp_  = rev ? (L_SEQ-1-t_) : t_;                                  \
    const bool act_ = tp_ < lenb;                                               \
    const bool ap_  = (t_ == 0) || ((rev ? (L_SEQ - t_) : (t_-1)) < lenb);      \
    f32x4 a0a={0,0,0,0}, a0b={0,0,0,0}, a1a={0,0,0,0}, a1b={0,0,0,0};           \
    {                                                                           \
      const unsigned short* pzz = &ZZb[0];                                      \
      const unsigned short* pk0 = ap_ ? (Brow + 64*((PAR)^1)       + 8*g) : pzz;\
      const unsigned short* pk1 = ap_ ? (Brow + 64*((PAR)^1) + 32  + 8*g) : pzz;\
      const unsigned short* ph2 = ap_ ? (Brow + 128 + 64*((PAR)^1)      + 8*g) : pzz;\
      const unsigned short* ph3 = ap_ ? (Brow + 128 + 64*((PAR)^1) + 32 + 8*g) : pzz;\
      bf16x8 bk0 = *(const bf16x8*)pk0;                                         \
      bf16x8 bk1 = *(const bf16x8*)pk1;                                         \
      bf16x8 bx  = *(const bf16x8*)(Brow + 256 + 32*(PAR) + 8*g);               \
      bf16x8 bh2 = *(const bf16x8*)ph2;                                         \
      bf16x8 bh3 = *(const bf16x8*)ph3;                                         \
      a0a = __builtin_amdgcn_mfma_f32_16x16x32_bf16(A0[0][0], bk0, a0a,0,0,0);  \
      a0b = __builtin_amdgcn_mfma_f32_16x16x32_bf16(A0[1][0], bk0, a0b,0,0,0);  \
      a0a = __builtin_amdgcn_mfma_f32_16x16x32_bf16(A0[0][1], bk1, a0a,0,0,0);  \
      a0b = __builtin_amdgcn_mfma_f32_16x16x32_bf16(A0[1][1], bk1, a0b,0,0,0);  \
      a0a = __builtin_amdgcn_mfma_f32_16x16x32_bf16(A0[0][2], bx,  a0a,0,0,0);  \
      a0b = __builtin_amdgcn_mfma_f32_16x16x32_bf16(A0[1][2], bx,  a0b,0,0,0);  \
      a1a = __builtin_amdgcn_mfma_f32_16x16x32_bf16(A1[0][2], bh2, a1a,0,0,0);  \
      a1b = __builtin_amdgcn_mfma_f32_16x16x32_bf16(A1[1][2], bh2, a1b,0,0,0);  \
      a1a = __builtin_amdgcn_mfma_f32_16x16x32_bf16(A1[0][3], bh3, a1a,0,0,0);  \
      a1b = __builtin_amdgcn_mfma_f32_16x16x32_bf16(A1[1][3], bh3, a1b,0,0,0);  \
    }                                                                           \
    {                                                                           \
      float h0v = cell_act(__builtin_fmaf(wx[0][0],h_d,a0a[0]),                 \
                           __builtin_fmaf(wx[1][0],h_d,a0a[1]),                 \
                           __builtin_fmaf(wx[2][0],h_d,a0b[0]),                 \
                           __builtin_fmaf(wx[3][0],h_d,a0b[1]),                 \
                           bp0[0][0],bp0[1][0],bp0[2][0],bp0[3][0], c00, act_); \
      float h1v = cell_act(__builtin_fmaf(wx[0][1],h_d,a0a[2]),                 \
                           __builtin_fmaf(wx[1][1],h_d,a0a[3]),                 \
                           __builtin_fmaf(wx[2][1],h_d,a0b[2]),                 \
                           __builtin_fmaf(wx[3][1],h_d,a0b[3]),                 \
                           bp0[0][1],bp0[1][1],bp0[2][1],bp0[3][1], c01, act_); \
      *(unsigned int*)&XB[r16][64*(PAR) + 8*w + 2*g] = cvtpk(h0v, h1v);         \
      if (xload){                                                               \
        unsigned int* dst = (unsigned int*)&XB[l][256 + 32*((PAR)^1)];          \
        dst[0] = cvtpk(xr0, xr1);                                               \
        dst[1] = cvtpk(xr2, xr3);                                               \
        XB[l][256 + 32*((PAR)^1) + 4] = (unsigned short)cvtpk(xr4, xr4);        \
        int ts = t_ + 2;                                                        \
        int tpn = rev ? (L_SEQ-1-ts) : ts;                                      \
        tpn = tpn < 0 ? 0 : (tpn >= L_SEQ ? L_SEQ-1 : tpn);                     \
        const float4 v_ = *(const float4*)(dP + ((size_t)(b0+l)*L_SEQ + tpn)*4);\
        xr0=v_.x; xr1=v_.y; xr2=v_.z; xr3=v_.w;                                 \
        xr4 = eps[(size_t)(b0+l)*L_SEQ + tpn];                                  \
      }                                                                         \
    }                                                                           \
    __syncthreads();   /* B2: raw h0(t) + x(t+1) visible */                     \
    {                                                                           \
      bf16x8 bk0 = *(const bf16x8*)(Brow + 64*(PAR)      + 8*g);                \
      bf16x8 bk1 = *(const bf16x8*)(Brow + 64*(PAR) + 32 + 8*g);                \
      a1a = __builtin_amdgcn_mfma_f32_16x16x32_bf16(A1[0][0], bk0, a1a,0,0,0);  \
      a1b = __builtin_amdgcn_mfma_f32_16x16x32_bf16(A1[1][0], bk0, a1b,0,0,0);  \
      a1a = __builtin_amdgcn_mfma_f32_16x16x32_bf16(A1[0][1], bk1, a1a,0,0,0);  \
      a1b = __builtin_amdgcn_mfma_f32_16x16x32_bf16(A1[1][1], bk1, a1b,0,0,0);  \
    }                                                                           \
    {                                                                           \
      if (l < 16) dpart[(PAR)^1][l] = 0.f;  /* safe: post-B2, readers done */   \
      float h0v = cell_act(a1a[0],a1a[1],a1b[0],a1b[1],                         \
                           bp1[0][0],bp1[1][0],bp1[2][0],bp1[3][0], c10, act_); \
      float h1v = cell_act(a1a[2],a1a[3],a1b[2],a1b[3],                         \
                           bp1[0][1],bp1[1][1],bp1[2][1],bp1[3][1], c11, act_); \
      *(unsigned int*)&XB[r16][128 + 64*(PAR) + 8*w + 2*g] = cvtpk(h0v, h1v);   \
      float s_ = __builtin_fmaf(wh0, h0v, wh1*h1v);                             \
      s_ += __shfl_xor(s_, 16, 64);                                             \
      s_ += __shfl_xor(s_, 32, 64);                                             \
      if (l < 16) atomicAdd(&dpart[(PAR)][l], s_);                              \
    }                                                                           \
    __syncthreads();   /* B4: h1(t) + dpart sums visible */                     \
    {                                                                           \
      const float dsum_ = bhead + dpart[(PAR)][r16];                            \
      const float hp_ = h_d;                                                    \
      if (act_) h_d += dsum_;                                                   \
      if (w == 0 && l < 8){                                                     \
        out[(size_t)(b0+l)*L_SEQ + tp_] = hp_;                                  \
        out[(size_t)B_TOT*L_SEQ + (size_t)(b0+l)*L_SEQ + tp_] = dsum_;          \
      }                                                                         \
    }                                                                           \
  }

__global__ __launch_bounds__(512, 2)
void dh_lstm(const float* __restrict__ dP, const float* __restrict__ eps,
             const float* __restrict__ Wih0, const float* __restrict__ Whh0,
             const float* __restrict__ bih0, const float* __restrict__ bhh0,
             const float* __restrict__ Wih1, const float* __restrict__ Whh1,
             const float* __restrict__ bih1, const float* __restrict__ bhh1,
             const float* __restrict__ Whead, const float* __restrict__ bhead_p,
             const int* __restrict__ lengths, const int* __restrict__ revp,
             float* __restrict__ out)
{
  __shared__ unsigned short XB[16][XBS];
  __shared__ float dpart[2][16];                 // double-buffered col sums
  __shared__ __align__(16) unsigned short ZZb[16]; // 32B zero block (masked reads)

  const int tid = threadIdx.x;
  const int l   = tid & 63;
  const int w   = tid >> 6;        // wave id: owns hidden units [8w, 8w+8)
  const int g   = l >> 4;          // lanegroup
  const int r16 = l & 15;          // batch slot (0..7 real)
  const int b0  = blockIdx.x * BQ;
  const int rev = revp[0];

  { // zero LDS
    unsigned int* p = (unsigned int*)&XB[0][0];
    for (int i = tid; i < 16*XBS/2; i += 512) p[i] = 0u;
    if (tid < 32) ((float*)dpart)[tid] = 0.f;
    if (tid < 16) ZZb[tid] = 0;
  }

  // ---- weights -> registers as MFMA A-fragments (permuted gate rows) ----
  bf16x8 A0[2][3], A1[2][4];
  {
    const int u  = r16 >> 1;
    const int t0 = r16 & 1;
#pragma unroll
    for (int tau = 0; tau < 2; ++tau){
      const int j = 64*(2*tau + t0) + 8*w + u;
#pragma unroll
      for (int k = 0; k < 3; ++k){      // L0: [Whh0(64) | Wih0 cols 0..5 | 0pad]
        bf16x8 a;
#pragma unroll
        for (int e = 0; e < 8; ++e){
          const int c = 32*k + 8*g + e;
          float v = 0.f;
          if (c < 64) v = Whh0[j*64 + c];
          else if (c < 70) v = Wih0[j*6 + (c-64)];
          a[e] = (short)f2bf(v);
        }
        A0[tau][k] = a;
      }
#pragma unroll
      for (int k = 0; k < 4; ++k){      // L1: [Wih1(64) | Whh1(64)]
        bf16x8 a;
#pragma unroll
        for (int e = 0; e < 8; ++e){
          const int c = 32*k + 8*g + e;
          const float v = (c < 64) ? Wih1[j*64 + c] : Whh1[j*64 + (c-64)];
          a[e] = (short)f2bf(v);
        }
        A1[tau][k] = a;
      }
    }
  }

  // act-side per-lane constants: hidden u = 2g + jslot
  float bp0[4][2], bp1[4][2], wx[4][2];
#pragma unroll
  for (int t4 = 0; t4 < 4; ++t4){
#pragma unroll
    for (int j = 0; j < 2; ++j){
      const int jj = 64*t4 + 8*w + 2*g + j;
      const float sc = (t4 == 2) ? 2.8853900817779268f : -1.4426950408889634f;
      bp0[t4][j] = sc * (bih0[jj] + bhh0[jj]);
      bp1[t4][j] = sc * (bih1[jj] + bhh1[jj]);
      wx[t4][j]  = Wih0[jj*6 + 5];     // h_d column of W_ih0 (done on VALU)
    }
  }
  const float wh0 = Whead[8*w + 2*g + 0];
  const float wh1 = Whead[8*w + 2*g + 1];
  const float bhead = bhead_p[0];
  const int   lenb  = lengths[b0 + (r16 & 7)];

  __syncthreads();

  // x prefetch pipeline: x(t) lives in buf t&1; wave1 lanes 0..7 manage it.
  float xr0=0,xr1=0,xr2=0,xr3=0,xr4=0;
  const bool xload = (w == 1) && (l < 8);
  if (xload){
    const int t0p = rev ? (L_SEQ-1) : 0;
    const float4 v = *(const float4*)(dP + ((size_t)(b0+l)*L_SEQ + t0p)*4);
    const float ev = eps[(size_t)(b0+l)*L_SEQ + t0p];
    unsigned int* dst = (unsigned int*)&XB[l][256];
    dst[0] = cvtpk(v.x, v.y);
    dst[1] = cvtpk(v.z, v.w);
    XB[l][256+4] = (unsigned short)cvtpk(ev, ev);
    const int t1p = rev ? (L_SEQ-2) : 1;
    const float4 v1 = *(const float4*)(dP + ((size_t)(b0+l)*L_SEQ + t1p)*4);
    xr0=v1.x; xr1=v1.y; xr2=v1.z; xr3=v1.w;
    xr4 = eps[(size_t)(b0+l)*L_SEQ + t1p];
  }
  __syncthreads();

  float c00=0,c01=0,c10=0,c11=0, h_d=0;
  const unsigned short* Brow = &XB[r16][0];

#pragma unroll 1
  for (int t2 = 0; t2 < L_SEQ; t2 += 2){
    STEP(0, t2)
    STEP(1, t2 + 1)
  }
}

extern "C" void kernel_launch(void* const* d_in, const int* in_sizes, int n_in,
                              void* d_out, int out_size, void* d_ws, size_t ws_size,
                              hipStream_t stream) {
  (void)in_sizes; (void)n_in; (void)d_ws; (void)ws_size; (void)out_size;
  dh_lstm<<<dim3(NBLK), dim3(512), 0, stream>>>(
      (const float*)d_in[0],  (const float*)d_in[1],
      (const float*)d_in[2],  (const float*)d_in[3],
      (const float*)d_in[4],  (const float*)d_in[5],
      (const float*)d_in[6],  (const float*)d_in[7],
      (const float*)d_in[8],  (const float*)d_in[9],
      (const float*)d_in[10], (const float*)d_in[11],
      (const int*)d_in[12],   (const int*)d_in[13],
      (float*)d_out);
}